// Round 1
// baseline (960.376 us; speedup 1.0000x reference)
//
#include <hip/hip_runtime.h>
#include <hip/hip_bf16.h>

typedef unsigned short u16;
typedef __attribute__((ext_vector_type(8))) unsigned short us8;

#define TW 1088  // T row width: 64*16 (T) + 64 (B bias term)

static __device__ __forceinline__ u16 f2b(float f) {
    union { float f; unsigned u; } v; v.f = f;
    unsigned r = v.u + 0x7FFF + ((v.u >> 16) & 1);  // round-nearest-even
    return (u16)(r >> 16);
}
static __device__ __forceinline__ float b2f(u16 b) {
    union { unsigned u; float f; } v; v.u = ((unsigned)b) << 16; return v.f;
}

// ---- one-time: transpose w_ih, w_hh [192,64] -> [64,192] for coalesced reads
__global__ __launch_bounds__(256) void k_transpose_w(
        const float* __restrict__ wih, const float* __restrict__ whh,
        float* __restrict__ wihT, float* __restrict__ whhT) {
    int idx = blockIdx.x * 256 + threadIdx.x;
    if (idx < 192 * 64) {
        int i = idx / 192, c = idx % 192;
        wihT[i * 192 + c] = wih[c * 64 + i];
        whhT[i * 192 + c] = whh[c * 64 + i];
    }
}

// ---- lin0: out = relu(x[N,32] @ w[64,32]^T + b)
__global__ __launch_bounds__(256) void k_lin0(
        const float* __restrict__ x, const float* __restrict__ w,
        const float* __restrict__ b, float* __restrict__ out, int N) {
    __shared__ float xs[4][32];
    int n0 = blockIdx.x * 4;
    int t = threadIdx.x;
    if (t < 128) {
        int n = n0 + (t >> 5);
        if (n < N) xs[t >> 5][t & 31] = x[(size_t)n * 32 + (t & 31)];
    }
    __syncthreads();
    int c = t & 63, g = t >> 6;
    int n = n0 + g;
    if (n < N) {
        float acc = b[c];
        #pragma unroll
        for (int i = 0; i < 32; i++) acc += xs[g][i] * w[c * 32 + i];
        out[(size_t)n * 64 + c] = fmaxf(acc, 0.f);
    }
}

// ---- A: T[n, o*16+k] = sum_i x[n,i]*nn_w[i*1024 + o*16+k]; T[n,1024+o] = sum_i x[n,i]*nn_b[i*64+o]
// tile: 16 nodes/block, 256 threads, each thread 4 cols x 16 nodes
__global__ __launch_bounds__(256) void k_A(
        const float* __restrict__ x, const float* __restrict__ nn_w,
        const float* __restrict__ nn_b, u16* __restrict__ T, int N) {
    __shared__ float xs[16][64];
    int n0 = blockIdx.x * 16;
    int t = threadIdx.x;
    for (int r = t; r < 16 * 64; r += 256) {
        int n = n0 + (r >> 6);
        xs[r >> 6][r & 63] = (n < N) ? x[(size_t)n * 64 + (r & 63)] : 0.f;
    }
    __syncthreads();

    int c = t * 4;  // cols c..c+3 of 1024
    float acc[16][4];
    #pragma unroll
    for (int n = 0; n < 16; n++)
        acc[n][0] = acc[n][1] = acc[n][2] = acc[n][3] = 0.f;
    for (int i = 0; i < 64; i += 4) {
        float4 w0 = *(const float4*)(nn_w + (size_t)(i + 0) * 1024 + c);
        float4 w1 = *(const float4*)(nn_w + (size_t)(i + 1) * 1024 + c);
        float4 w2 = *(const float4*)(nn_w + (size_t)(i + 2) * 1024 + c);
        float4 w3 = *(const float4*)(nn_w + (size_t)(i + 3) * 1024 + c);
        #pragma unroll
        for (int n = 0; n < 16; n++) {
            float4 xv = *(const float4*)(&xs[n][i]);
            acc[n][0] += xv.x * w0.x + xv.y * w1.x + xv.z * w2.x + xv.w * w3.x;
            acc[n][1] += xv.x * w0.y + xv.y * w1.y + xv.z * w2.y + xv.w * w3.y;
            acc[n][2] += xv.x * w0.z + xv.y * w1.z + xv.z * w2.z + xv.w * w3.z;
            acc[n][3] += xv.x * w0.w + xv.y * w1.w + xv.z * w2.w + xv.w * w3.w;
        }
    }
    #pragma unroll
    for (int n = 0; n < 16; n++) {
        int nn = n0 + n;
        if (nn < N) {
            ushort4 pk;
            pk.x = f2b(acc[n][0]); pk.y = f2b(acc[n][1]);
            pk.z = f2b(acc[n][2]); pk.w = f2b(acc[n][3]);
            *(ushort4*)(T + (size_t)nn * TW + c) = pk;
        }
    }
    // bias-columns 1024..1087: 4 groups x 4 nodes, 64 cols
    int c2 = t & 63, g = t >> 6;
    float accb[4] = {0.f, 0.f, 0.f, 0.f};
    for (int i = 0; i < 64; i++) {
        float wb = nn_b[i * 64 + c2];
        #pragma unroll
        for (int n = 0; n < 4; n++) accb[n] += xs[g * 4 + n][i] * wb;
    }
    #pragma unroll
    for (int n = 0; n < 4; n++) {
        int nn = n0 + g * 4 + n;
        if (nn < N) T[(size_t)nn * TW + 1024 + c2] = f2b(accb[n]);
    }
}

// ---- B: per-edge msg + scatter. 1 wave per edge, lane o in [0,64)
__global__ __launch_bounds__(256) void k_B(
        const u16* __restrict__ T, const int* __restrict__ ei,
        const float* __restrict__ ea, float* __restrict__ agg, int E) {
    int gid = blockIdx.x * 256 + threadIdx.x;
    int e = gid >> 6, o = gid & 63;
    if (e >= E) return;
    int src = ei[e], dst = ei[E + e];
    const float4* ea4 = (const float4*)(ea + (size_t)e * 16);
    float4 a0 = ea4[0], a1 = ea4[1], a2 = ea4[2], a3 = ea4[3];
    const u16* Tr = T + (size_t)src * TW;
    us8 v0 = *(const us8*)(Tr + o * 16);
    us8 v1 = *(const us8*)(Tr + o * 16 + 8);
    float acc = b2f(Tr[1024 + o]);
    acc += a0.x * b2f(v0[0]) + a0.y * b2f(v0[1]) + a0.z * b2f(v0[2]) + a0.w * b2f(v0[3]);
    acc += a1.x * b2f(v0[4]) + a1.y * b2f(v0[5]) + a1.z * b2f(v0[6]) + a1.w * b2f(v0[7]);
    acc += a2.x * b2f(v1[0]) + a2.y * b2f(v1[1]) + a2.z * b2f(v1[2]) + a2.w * b2f(v1[3]);
    acc += a3.x * b2f(v1[4]) + a3.y * b2f(v1[5]) + a3.z * b2f(v1[6]) + a3.w * b2f(v1[7]);
    atomicAdd(agg + (size_t)dst * 64 + o, acc);
}

// ---- C1: m = relu(agg + x@root + conv_b). 32 nodes/block, 256 thr (4 grp x 8 nodes)
__global__ __launch_bounds__(256) void k_C1(
        const float* __restrict__ x, const float* __restrict__ agg,
        const float* __restrict__ root, const float* __restrict__ conv_b,
        float* __restrict__ m, int N) {
    __shared__ float xs[32][64];
    int n0 = blockIdx.x * 32;
    int t = threadIdx.x;
    for (int r = t; r < 32 * 64; r += 256) {
        int n = n0 + (r >> 6);
        xs[r >> 6][r & 63] = (n < N) ? x[(size_t)n * 64 + (r & 63)] : 0.f;
    }
    __syncthreads();
    int c = t & 63, g = t >> 6;
    float acc[8];
    #pragma unroll
    for (int n = 0; n < 8; n++) acc[n] = 0.f;
    for (int i = 0; i < 64; i++) {
        float rv = root[i * 64 + c];
        #pragma unroll
        for (int n = 0; n < 8; n++) acc[n] += xs[g * 8 + n][i] * rv;
    }
    float cb = conv_b[c];
    #pragma unroll
    for (int n = 0; n < 8; n++) {
        int nn = n0 + g * 8 + n;
        if (nn < N)
            m[(size_t)nn * 64 + c] = fmaxf(acc[n] + agg[(size_t)nn * 64 + c] + cb, 0.f);
    }
}

// ---- C2: gi = m@w_ih^T + b_ih; gh = h@w_hh^T + b_hh; GRU gates -> hout
// 16 nodes/block, 192 threads
__global__ __launch_bounds__(192) void k_C2(
        const float* __restrict__ m, const float* __restrict__ h,
        const float* __restrict__ wihT, const float* __restrict__ whhT,
        const float* __restrict__ b_ih, const float* __restrict__ b_hh,
        float* __restrict__ hout, int N) {
    __shared__ float ms[16][64], hs[16][64], gi[16][192], gh[16][192];
    int n0 = blockIdx.x * 16;
    int t = threadIdx.x;
    for (int r = t; r < 16 * 64; r += 192) {
        int n = n0 + (r >> 6);
        float hv = 0.f, mv = 0.f;
        if (n < N) {
            hv = h[(size_t)n * 64 + (r & 63)];
            mv = m[(size_t)n * 64 + (r & 63)];
        }
        hs[r >> 6][r & 63] = hv;
        ms[r >> 6][r & 63] = mv;
    }
    __syncthreads();
    int c = t;  // 0..191
    float agi[16], agh[16];
    #pragma unroll
    for (int n = 0; n < 16; n++) { agi[n] = 0.f; agh[n] = 0.f; }
    for (int i = 0; i < 64; i++) {
        float wi = wihT[i * 192 + c];
        float wh = whhT[i * 192 + c];
        #pragma unroll
        for (int n = 0; n < 16; n++) {
            agi[n] += ms[n][i] * wi;
            agh[n] += hs[n][i] * wh;
        }
    }
    float bi = b_ih[c], bh = b_hh[c];
    #pragma unroll
    for (int n = 0; n < 16; n++) { gi[n][c] = agi[n] + bi; gh[n][c] = agh[n] + bh; }
    __syncthreads();
    for (int idx = t; idx < 16 * 64; idx += 192) {
        int n = idx >> 6, j = idx & 63;
        int nn = n0 + n;
        if (nn < N) {
            float r = 1.f / (1.f + __expf(-(gi[n][j] + gh[n][j])));
            float z = 1.f / (1.f + __expf(-(gi[n][64 + j] + gh[n][64 + j])));
            float nt = tanhf(gi[n][128 + j] + r * gh[n][128 + j]);
            hout[(size_t)nn * 64 + j] = (1.f - z) * nt + z * hs[n][j];
        }
    }
}

extern "C" void kernel_launch(void* const* d_in, const int* in_sizes, int n_in,
                              void* d_out, int out_size, void* d_ws, size_t ws_size,
                              hipStream_t stream) {
    const float* x_in   = (const float*)d_in[0];
    const int*   ei     = (const int*)d_in[1];
    const float* ea     = (const float*)d_in[2];
    const float* lin0_w = (const float*)d_in[3];
    const float* lin0_b = (const float*)d_in[4];
    const float* nn_w   = (const float*)d_in[5];
    const float* nn_b   = (const float*)d_in[6];
    const float* root   = (const float*)d_in[7];
    const float* conv_b = (const float*)d_in[8];
    const float* w_ih   = (const float*)d_in[9];
    const float* w_hh   = (const float*)d_in[10];
    const float* b_ih   = (const float*)d_in[11];
    const float* b_hh   = (const float*)d_in[12];

    int N = in_sizes[0] / 32;
    int E = in_sizes[1] / 2;

    // workspace layout
    char* ws = (char*)d_ws;
    size_t off = 0;
    auto alloc = [&](size_t bytes) { char* p = ws + off; off += (bytes + 255) & ~(size_t)255; return p; };
    float* xbuf = (float*)alloc((size_t)N * 64 * 4);
    float* agg  = (float*)alloc((size_t)N * 64 * 4);
    float* mbuf = (float*)alloc((size_t)N * 64 * 4);
    float* wihT = (float*)alloc(192 * 64 * 4);
    float* whhT = (float*)alloc(192 * 64 * 4);
    u16*   Tbuf = (u16*)alloc((size_t)N * TW * 2);
    (void)ws_size;

    hipLaunchKernelGGL(k_transpose_w, dim3(48), dim3(256), 0, stream, w_ih, w_hh, wihT, whhT);
    hipLaunchKernelGGL(k_lin0, dim3((N + 3) / 4), dim3(256), 0, stream, x_in, lin0_w, lin0_b, xbuf, N);

    for (int it = 0; it < 3; it++) {
        hipLaunchKernelGGL(k_A, dim3((N + 15) / 16), dim3(256), 0, stream, xbuf, nn_w, nn_b, Tbuf, N);
        hipMemsetAsync(agg, 0, (size_t)N * 64 * 4, stream);
        hipLaunchKernelGGL(k_B, dim3((E * 64 + 255) / 256), dim3(256), 0, stream, Tbuf, ei, ea, agg, E);
        hipLaunchKernelGGL(k_C1, dim3((N + 31) / 32), dim3(256), 0, stream, xbuf, agg, root, conv_b, mbuf, N);
        float* hout = (it == 2) ? (float*)d_out : xbuf;
        hipLaunchKernelGGL(k_C2, dim3((N + 15) / 16), dim3(192), 0, stream, mbuf, xbuf, wihT, whhT, b_ih, b_hh, hout, N);
    }
}

// Round 2
// 654.298 us; speedup vs baseline: 1.4678x; 1.4678x over previous
//
#include <hip/hip_runtime.h>
#include <hip/hip_bf16.h>

typedef unsigned short u16;
typedef __attribute__((ext_vector_type(8))) unsigned short us8;
typedef __attribute__((ext_vector_type(8))) short s8v;     // MFMA bf16 A/B frag (4 VGPR)
typedef __attribute__((ext_vector_type(4))) float f32x4;   // MFMA C/D frag

#define TW 1088  // T row width: 64*16 (T) + 64 (B bias term)

static __device__ __forceinline__ u16 f2b(float f) {
    union { float f; unsigned u; } v; v.f = f;
    unsigned r = v.u + 0x7FFF + ((v.u >> 16) & 1);  // round-nearest-even
    return (u16)(r >> 16);
}
static __device__ __forceinline__ float b2f(u16 b) {
    union { unsigned u; float f; } v; v.u = ((unsigned)b) << 16; return v.f;
}

// ---- one-time: transpose w_ih, w_hh [192,64] -> [64,192] for coalesced reads
__global__ __launch_bounds__(256) void k_transpose_w(
        const float* __restrict__ wih, const float* __restrict__ whh,
        float* __restrict__ wihT, float* __restrict__ whhT) {
    int idx = blockIdx.x * 256 + threadIdx.x;
    if (idx < 192 * 64) {
        int i = idx / 192, c = idx % 192;
        wihT[i * 192 + c] = wih[c * 64 + i];
        whhT[i * 192 + c] = whh[c * 64 + i];
    }
}

// ---- one-time: pack W' = [nn_w | nn_b-as-matrix] (shape [64 k][1088 col]) into
// MFMA A-fragment layout, split bf16 hi/lo.
// Layout: idx = ((kc*68 + ct)*64 + lane)*8 + j ; k = kc*32 + (lane>>4)*8 + j ;
//         col = ct*16 + (lane&15)
__global__ __launch_bounds__(256) void k_prepW(
        const float* __restrict__ nn_w, const float* __restrict__ nn_b,
        u16* __restrict__ wf_hi, u16* __restrict__ wf_lo) {
    int idx = blockIdx.x * 256 + threadIdx.x;
    if (idx >= 2 * 68 * 64 * 8) return;
    int j = idx & 7, lane = (idx >> 3) & 63;
    int rest = idx >> 9;
    int ct = rest % 68, kc = rest / 68;
    int k = kc * 32 + ((lane >> 4) * 8) + j;
    int col = ct * 16 + (lane & 15);
    float v = (col < 1024) ? nn_w[(size_t)k * 1024 + col]
                           : nn_b[(size_t)k * 64 + (col - 1024)];
    u16 hi = f2b(v);
    u16 lo = f2b(v - b2f(hi));
    wf_hi[idx] = hi;
    wf_lo[idx] = lo;
}

// ---- lin0: out = relu(x[N,32] @ w[64,32]^T + b)
__global__ __launch_bounds__(256) void k_lin0(
        const float* __restrict__ x, const float* __restrict__ w,
        const float* __restrict__ b, float* __restrict__ out, int N) {
    __shared__ float xs[4][32];
    int n0 = blockIdx.x * 4;
    int t = threadIdx.x;
    if (t < 128) {
        int n = n0 + (t >> 5);
        if (n < N) xs[t >> 5][t & 31] = x[(size_t)n * 32 + (t & 31)];
    }
    __syncthreads();
    int c = t & 63, g = t >> 6;
    int n = n0 + g;
    if (n < N) {
        float acc = b[c];
        #pragma unroll
        for (int i = 0; i < 32; i++) acc += xs[g][i] * w[c * 32 + i];
        out[(size_t)n * 64 + c] = fmaxf(acc, 0.f);
    }
}

// ---- A (MFMA): T[n, col] = sum_k x[n,k] * W'[k, col], split-bf16 (~fp32 exact),
// output rounded to bf16. Block: 4 waves x 16 nodes = 64 nodes, 17 col-tiles
// (grid.y=4 covers 68). W frags staged via LDS per K=32 phase, shared by waves.
__global__ __launch_bounds__(256) void k_A_mfma(
        const float* __restrict__ X, const u16* __restrict__ wf_hi,
        const u16* __restrict__ wf_lo, u16* __restrict__ T, int N) {
    __shared__ __align__(16) u16 lw_hi[17 * 512];
    __shared__ __align__(16) u16 lw_lo[17 * 512];
    int t = threadIdx.x;
    int l = t & 63, w = t >> 6;
    int n0 = blockIdx.x * 64 + w * 16;
    int ct0 = blockIdx.y * 17;
    int node = n0 + (l & 15);
    int nload = node < N ? node : N - 1;
    const float* xrow = X + (size_t)nload * 64 + ((l >> 4) * 8);

    f32x4 acc[17];
    #pragma unroll
    for (int ct = 0; ct < 17; ct++) acc[ct] = (f32x4)(0.f);

    for (int kc = 0; kc < 2; kc++) {
        if (kc) __syncthreads();  // phase-0 compute done before LDS overwrite
        const uint4* gh = (const uint4*)(wf_hi + (size_t)(kc * 68 + ct0) * 512);
        const uint4* gl = (const uint4*)(wf_lo + (size_t)(kc * 68 + ct0) * 512);
        uint4* lh = (uint4*)lw_hi;
        uint4* ll = (uint4*)lw_lo;
        for (int i = t; i < 17 * 512 / 8; i += 256) { lh[i] = gh[i]; ll[i] = gl[i]; }
        __syncthreads();

        // X fragment (B operand): lane -> node = n0+(l&15), k = kc*32+(l>>4)*8+j
        float4 xa = *(const float4*)(xrow + kc * 32);
        float4 xb = *(const float4*)(xrow + kc * 32 + 4);
        float xf[8] = {xa.x, xa.y, xa.z, xa.w, xb.x, xb.y, xb.z, xb.w};
        s8v x_hi, x_lo;
        #pragma unroll
        for (int j = 0; j < 8; j++) {
            u16 h = f2b(xf[j]);
            x_hi[j] = (short)h;
            x_lo[j] = (short)f2b(xf[j] - b2f(h));
        }
        #pragma unroll
        for (int ct = 0; ct < 17; ct++) {
            s8v whi = *(const s8v*)(lw_hi + ct * 512 + l * 8);
            s8v wlo = *(const s8v*)(lw_lo + ct * 512 + l * 8);
            acc[ct] = __builtin_amdgcn_mfma_f32_16x16x32_bf16(whi, x_hi, acc[ct], 0, 0, 0);
            acc[ct] = __builtin_amdgcn_mfma_f32_16x16x32_bf16(wlo, x_hi, acc[ct], 0, 0, 0);
            acc[ct] = __builtin_amdgcn_mfma_f32_16x16x32_bf16(whi, x_lo, acc[ct], 0, 0, 0);
        }
    }

    // D: col(lane&15)=node, row((lane>>4)*4+reg)=W-col within tile -> 4 consecutive
    // T columns per lane -> 8B packed store.
    if (node < N) {
        int g = l >> 4;
        u16* trow = T + (size_t)node * TW;
        #pragma unroll
        for (int ct = 0; ct < 17; ct++) {
            ushort4 pk;
            pk.x = f2b(acc[ct][0]);
            pk.y = f2b(acc[ct][1]);
            pk.z = f2b(acc[ct][2]);
            pk.w = f2b(acc[ct][3]);
            *(ushort4*)(trow + (ct0 + ct) * 16 + g * 4) = pk;
        }
    }
}

// ---- B: per-edge msg + scatter. 1 wave per edge, lane o in [0,64)
__global__ __launch_bounds__(256) void k_B(
        const u16* __restrict__ T, const int* __restrict__ ei,
        const float* __restrict__ ea, float* __restrict__ agg, int E) {
    int gid = blockIdx.x * 256 + threadIdx.x;
    int e = gid >> 6, o = gid & 63;
    if (e >= E) return;
    int src = ei[e], dst = ei[E + e];
    const float4* ea4 = (const float4*)(ea + (size_t)e * 16);
    float4 a0 = ea4[0], a1 = ea4[1], a2 = ea4[2], a3 = ea4[3];
    const u16* Tr = T + (size_t)src * TW;
    us8 v0 = *(const us8*)(Tr + o * 16);
    us8 v1 = *(const us8*)(Tr + o * 16 + 8);
    float acc = b2f(Tr[1024 + o]);
    acc += a0.x * b2f(v0[0]) + a0.y * b2f(v0[1]) + a0.z * b2f(v0[2]) + a0.w * b2f(v0[3]);
    acc += a1.x * b2f(v0[4]) + a1.y * b2f(v0[5]) + a1.z * b2f(v0[6]) + a1.w * b2f(v0[7]);
    acc += a2.x * b2f(v1[0]) + a2.y * b2f(v1[1]) + a2.z * b2f(v1[2]) + a2.w * b2f(v1[3]);
    acc += a3.x * b2f(v1[4]) + a3.y * b2f(v1[5]) + a3.z * b2f(v1[6]) + a3.w * b2f(v1[7]);
    atomicAdd(agg + (size_t)dst * 64 + o, acc);
}

// ---- C1: m = relu(agg + x@root + conv_b). 32 nodes/block, 256 thr (4 grp x 8 nodes)
__global__ __launch_bounds__(256) void k_C1(
        const float* __restrict__ x, const float* __restrict__ agg,
        const float* __restrict__ root, const float* __restrict__ conv_b,
        float* __restrict__ m, int N) {
    __shared__ float xs[32][64];
    int n0 = blockIdx.x * 32;
    int t = threadIdx.x;
    for (int r = t; r < 32 * 64; r += 256) {
        int n = n0 + (r >> 6);
        xs[r >> 6][r & 63] = (n < N) ? x[(size_t)n * 64 + (r & 63)] : 0.f;
    }
    __syncthreads();
    int c = t & 63, g = t >> 6;
    float acc[8];
    #pragma unroll
    for (int n = 0; n < 8; n++) acc[n] = 0.f;
    for (int i = 0; i < 64; i++) {
        float rv = root[i * 64 + c];
        #pragma unroll
        for (int n = 0; n < 8; n++) acc[n] += xs[g * 8 + n][i] * rv;
    }
    float cb = conv_b[c];
    #pragma unroll
    for (int n = 0; n < 8; n++) {
        int nn = n0 + g * 8 + n;
        if (nn < N)
            m[(size_t)nn * 64 + c] = fmaxf(acc[n] + agg[(size_t)nn * 64 + c] + cb, 0.f);
    }
}

// ---- C2: gi = m@w_ih^T + b_ih; gh = h@w_hh^T + b_hh; GRU gates -> hout
__global__ __launch_bounds__(192) void k_C2(
        const float* __restrict__ m, const float* __restrict__ h,
        const float* __restrict__ wihT, const float* __restrict__ whhT,
        const float* __restrict__ b_ih, const float* __restrict__ b_hh,
        float* __restrict__ hout, int N) {
    __shared__ float ms[16][64], hs[16][64], gi[16][192], gh[16][192];
    int n0 = blockIdx.x * 16;
    int t = threadIdx.x;
    for (int r = t; r < 16 * 64; r += 192) {
        int n = n0 + (r >> 6);
        float hv = 0.f, mv = 0.f;
        if (n < N) {
            hv = h[(size_t)n * 64 + (r & 63)];
            mv = m[(size_t)n * 64 + (r & 63)];
        }
        hs[r >> 6][r & 63] = hv;
        ms[r >> 6][r & 63] = mv;
    }
    __syncthreads();
    int c = t;  // 0..191
    float agi[16], agh[16];
    #pragma unroll
    for (int n = 0; n < 16; n++) { agi[n] = 0.f; agh[n] = 0.f; }
    for (int i = 0; i < 64; i++) {
        float wi = wihT[i * 192 + c];
        float wh = whhT[i * 192 + c];
        #pragma unroll
        for (int n = 0; n < 16; n++) {
            agi[n] += ms[n][i] * wi;
            agh[n] += hs[n][i] * wh;
        }
    }
    float bi = b_ih[c], bh = b_hh[c];
    #pragma unroll
    for (int n = 0; n < 16; n++) { gi[n][c] = agi[n] + bi; gh[n][c] = agh[n] + bh; }
    __syncthreads();
    for (int idx = t; idx < 16 * 64; idx += 192) {
        int n = idx >> 6, j = idx & 63;
        int nn = n0 + n;
        if (nn < N) {
            float r = 1.f / (1.f + __expf(-(gi[n][j] + gh[n][j])));
            float z = 1.f / (1.f + __expf(-(gi[n][64 + j] + gh[n][64 + j])));
            float nt = tanhf(gi[n][128 + j] + r * gh[n][128 + j]);
            hout[(size_t)nn * 64 + j] = (1.f - z) * nt + z * hs[n][j];
        }
    }
}

extern "C" void kernel_launch(void* const* d_in, const int* in_sizes, int n_in,
                              void* d_out, int out_size, void* d_ws, size_t ws_size,
                              hipStream_t stream) {
    const float* x_in   = (const float*)d_in[0];
    const int*   ei     = (const int*)d_in[1];
    const float* ea     = (const float*)d_in[2];
    const float* lin0_w = (const float*)d_in[3];
    const float* lin0_b = (const float*)d_in[4];
    const float* nn_w   = (const float*)d_in[5];
    const float* nn_b   = (const float*)d_in[6];
    const float* root   = (const float*)d_in[7];
    const float* conv_b = (const float*)d_in[8];
    const float* w_ih   = (const float*)d_in[9];
    const float* w_hh   = (const float*)d_in[10];
    const float* b_ih   = (const float*)d_in[11];
    const float* b_hh   = (const float*)d_in[12];

    int N = in_sizes[0] / 32;
    int E = in_sizes[1] / 2;

    // workspace layout
    char* ws = (char*)d_ws;
    size_t off = 0;
    auto alloc = [&](size_t bytes) { char* p = ws + off; off += (bytes + 255) & ~(size_t)255; return p; };
    float* xbuf = (float*)alloc((size_t)N * 64 * 4);
    float* agg  = (float*)alloc((size_t)N * 64 * 4);
    float* mbuf = (float*)alloc((size_t)N * 64 * 4);
    float* wihT = (float*)alloc(192 * 64 * 4);
    float* whhT = (float*)alloc(192 * 64 * 4);
    u16*   Tbuf = (u16*)alloc((size_t)N * TW * 2);
    u16*   wfhi = (u16*)alloc((size_t)2 * 68 * 64 * 8 * 2);
    u16*   wflo = (u16*)alloc((size_t)2 * 68 * 64 * 8 * 2);
    (void)ws_size;

    hipLaunchKernelGGL(k_transpose_w, dim3(48), dim3(256), 0, stream, w_ih, w_hh, wihT, whhT);
    hipLaunchKernelGGL(k_prepW, dim3(272), dim3(256), 0, stream, nn_w, nn_b, wfhi, wflo);
    hipLaunchKernelGGL(k_lin0, dim3((N + 3) / 4), dim3(256), 0, stream, x_in, lin0_w, lin0_b, xbuf, N);

    for (int it = 0; it < 3; it++) {
        hipLaunchKernelGGL(k_A_mfma, dim3((N + 63) / 64, 4), dim3(256), 0, stream, xbuf, wfhi, wflo, Tbuf, N);
        hipMemsetAsync(agg, 0, (size_t)N * 64 * 4, stream);
        hipLaunchKernelGGL(k_B, dim3((E * 64 + 255) / 256), dim3(256), 0, stream, Tbuf, ei, ea, agg, E);
        hipLaunchKernelGGL(k_C1, dim3((N + 31) / 32), dim3(256), 0, stream, xbuf, agg, root, conv_b, mbuf, N);
        float* hout = (it == 2) ? (float*)d_out : xbuf;
        hipLaunchKernelGGL(k_C2, dim3((N + 15) / 16), dim3(192), 0, stream, mbuf, xbuf, wihT, whhT, b_ih, b_hh, hout, N);
    }
}

// Round 3
// 421.005 us; speedup vs baseline: 2.2812x; 1.5541x over previous
//
#include <hip/hip_runtime.h>
#include <hip/hip_bf16.h>

typedef unsigned short u16;
typedef __attribute__((ext_vector_type(8))) unsigned short us8;
typedef __attribute__((ext_vector_type(8))) short s8v;     // MFMA bf16 A/B frag (4 VGPR)
typedef __attribute__((ext_vector_type(4))) float f32x4;   // MFMA C/D frag

#define TW 1088  // T row width: 64*16 (T) + 64 (B bias term)

static __device__ __forceinline__ u16 f2b(float f) {
    union { float f; unsigned u; } v; v.f = f;
    unsigned r = v.u + 0x7FFF + ((v.u >> 16) & 1);  // round-nearest-even
    return (u16)(r >> 16);
}
static __device__ __forceinline__ float b2f(u16 b) {
    union { unsigned u; float f; } v; v.u = ((unsigned)b) << 16; return v.f;
}
static __device__ __forceinline__ float sigm(float x) {
    return 1.f / (1.f + __expf(-x));
}
static __device__ __forceinline__ float tanh_f(float x) {
    return 1.f - 2.f / (__expf(2.f * x) + 1.f);
}

// ---- one-time: pack W' = [nn_w | nn_b-as-matrix] ([64 k][1088 col]) into MFMA
// A-frag layout, split bf16 hi/lo. idx=((kc*68+ct)*64+lane)*8+j
__global__ __launch_bounds__(256) void k_prepW(
        const float* __restrict__ nn_w, const float* __restrict__ nn_b,
        u16* __restrict__ wf_hi, u16* __restrict__ wf_lo) {
    int idx = blockIdx.x * 256 + threadIdx.x;
    if (idx >= 2 * 68 * 64 * 8) return;
    int j = idx & 7, lane = (idx >> 3) & 63;
    int rest = idx >> 9;
    int ct = rest % 68, kc = rest / 68;
    int k = kc * 32 + ((lane >> 4) * 8) + j;
    int col = ct * 16 + (lane & 15);
    float v = (col < 1024) ? nn_w[(size_t)k * 1024 + col]
                           : nn_b[(size_t)k * 64 + (col - 1024)];
    u16 hi = f2b(v);
    wf_hi[idx] = hi;
    wf_lo[idx] = f2b(v - b2f(hi));
}

// ---- one-time: pack W1=[root | w_hh^T] ([64 k][256 col], 16 ct) and
// W2=w_ih^T ([64 k][192 col], 12 ct) into MFMA A-frag layout, split hi/lo.
__global__ __launch_bounds__(256) void k_prepW12(
        const float* __restrict__ root, const float* __restrict__ w_hh,
        const float* __restrict__ w_ih, u16* __restrict__ w1hi, u16* __restrict__ w1lo,
        u16* __restrict__ w2hi, u16* __restrict__ w2lo) {
    int idx = blockIdx.x * 256 + threadIdx.x;
    if (idx < 16384) {
        int j = idx & 7, lane = (idx >> 3) & 63;
        int rest = idx >> 9;          // kc*16 + ct
        int ct = rest & 15, kc = rest >> 4;
        int k = kc * 32 + ((lane >> 4) * 8) + j;
        int col = ct * 16 + (lane & 15);
        float v = (col < 64) ? root[(size_t)k * 64 + col]
                             : w_hh[(size_t)(col - 64) * 64 + k];
        u16 hi = f2b(v);
        w1hi[idx] = hi;
        w1lo[idx] = f2b(v - b2f(hi));
    } else if (idx < 16384 + 12288) {
        int i2 = idx - 16384;
        int j = i2 & 7, lane = (i2 >> 3) & 63;
        int rest = i2 >> 9;           // kc*12 + ct
        int ct = rest % 12, kc = rest / 12;
        int k = kc * 32 + ((lane >> 4) * 8) + j;
        int col = ct * 16 + (lane & 15);
        float v = w_ih[(size_t)col * 64 + k];
        u16 hi = f2b(v);
        w2hi[i2] = hi;
        w2lo[i2] = f2b(v - b2f(hi));
    }
}

// ---- lin0: out = relu(x[N,32] @ w[64,32]^T + b)
__global__ __launch_bounds__(256) void k_lin0(
        const float* __restrict__ x, const float* __restrict__ w,
        const float* __restrict__ b, float* __restrict__ out, int N) {
    __shared__ float xs[4][32];
    int n0 = blockIdx.x * 4;
    int t = threadIdx.x;
    if (t < 128) {
        int n = n0 + (t >> 5);
        if (n < N) xs[t >> 5][t & 31] = x[(size_t)n * 32 + (t & 31)];
    }
    __syncthreads();
    int c = t & 63, g = t >> 6;
    int n = n0 + g;
    if (n < N) {
        float acc = b[c];
        #pragma unroll
        for (int i = 0; i < 32; i++) acc += xs[g][i] * w[c * 32 + i];
        out[(size_t)n * 64 + c] = fmaxf(acc, 0.f);
    }
}

// ---- A (MFMA): T[n,col] = sum_k x[n,k]*W'[k,col], split-bf16, bf16 out.
__global__ __launch_bounds__(256) void k_A_mfma(
        const float* __restrict__ X, const u16* __restrict__ wf_hi,
        const u16* __restrict__ wf_lo, u16* __restrict__ T, int N) {
    __shared__ __align__(16) u16 lw_hi[17 * 512];
    __shared__ __align__(16) u16 lw_lo[17 * 512];
    int t = threadIdx.x;
    int l = t & 63, w = t >> 6;
    int n0 = blockIdx.x * 64 + w * 16;
    int ct0 = blockIdx.y * 17;
    int node = n0 + (l & 15);
    int nload = node < N ? node : N - 1;
    const float* xrow = X + (size_t)nload * 64 + ((l >> 4) * 8);

    f32x4 acc[17];
    #pragma unroll
    for (int ct = 0; ct < 17; ct++) acc[ct] = (f32x4)(0.f);

    for (int kc = 0; kc < 2; kc++) {
        if (kc) __syncthreads();
        const uint4* gh = (const uint4*)(wf_hi + (size_t)(kc * 68 + ct0) * 512);
        const uint4* gl = (const uint4*)(wf_lo + (size_t)(kc * 68 + ct0) * 512);
        uint4* lh = (uint4*)lw_hi;
        uint4* ll = (uint4*)lw_lo;
        for (int i = t; i < 17 * 512 / 8; i += 256) { lh[i] = gh[i]; ll[i] = gl[i]; }
        __syncthreads();

        float4 xa = *(const float4*)(xrow + kc * 32);
        float4 xb = *(const float4*)(xrow + kc * 32 + 4);
        float xf[8] = {xa.x, xa.y, xa.z, xa.w, xb.x, xb.y, xb.z, xb.w};
        s8v x_hi, x_lo;
        #pragma unroll
        for (int j = 0; j < 8; j++) {
            u16 h = f2b(xf[j]);
            x_hi[j] = (short)h;
            x_lo[j] = (short)f2b(xf[j] - b2f(h));
        }
        #pragma unroll
        for (int ct = 0; ct < 17; ct++) {
            s8v whi = *(const s8v*)(lw_hi + ct * 512 + l * 8);
            s8v wlo = *(const s8v*)(lw_lo + ct * 512 + l * 8);
            acc[ct] = __builtin_amdgcn_mfma_f32_16x16x32_bf16(whi, x_hi, acc[ct], 0, 0, 0);
            acc[ct] = __builtin_amdgcn_mfma_f32_16x16x32_bf16(wlo, x_hi, acc[ct], 0, 0, 0);
            acc[ct] = __builtin_amdgcn_mfma_f32_16x16x32_bf16(whi, x_lo, acc[ct], 0, 0, 0);
        }
    }

    if (node < N) {
        int g = l >> 4;
        u16* trow = T + (size_t)node * TW;
        #pragma unroll
        for (int ct = 0; ct < 17; ct++) {
            ushort4 pk;
            pk.x = f2b(acc[ct][0]);
            pk.y = f2b(acc[ct][1]);
            pk.z = f2b(acc[ct][2]);
            pk.w = f2b(acc[ct][3]);
            *(ushort4*)(trow + (ct0 + ct) * 16 + g * 4) = pk;
        }
    }
}

// ---- B: per-edge msg + scatter. 1 wave per edge, lane o in [0,64)
__global__ __launch_bounds__(256) void k_B(
        const u16* __restrict__ T, const int* __restrict__ ei,
        const float* __restrict__ ea, float* __restrict__ agg, int E) {
    int gid = blockIdx.x * 256 + threadIdx.x;
    int e = gid >> 6, o = gid & 63;
    if (e >= E) return;
    int src = ei[e], dst = ei[E + e];
    const float4* ea4 = (const float4*)(ea + (size_t)e * 16);
    float4 a0 = ea4[0], a1 = ea4[1], a2 = ea4[2], a3 = ea4[3];
    const u16* Tr = T + (size_t)src * TW;
    us8 v0 = *(const us8*)(Tr + o * 16);
    us8 v1 = *(const us8*)(Tr + o * 16 + 8);
    float acc = b2f(Tr[1024 + o]);
    acc += a0.x * b2f(v0[0]) + a0.y * b2f(v0[1]) + a0.z * b2f(v0[2]) + a0.w * b2f(v0[3]);
    acc += a1.x * b2f(v0[4]) + a1.y * b2f(v0[5]) + a1.z * b2f(v0[6]) + a1.w * b2f(v0[7]);
    acc += a2.x * b2f(v1[0]) + a2.y * b2f(v1[1]) + a2.z * b2f(v1[2]) + a2.w * b2f(v1[3]);
    acc += a3.x * b2f(v1[4]) + a3.y * b2f(v1[5]) + a3.z * b2f(v1[6]) + a3.w * b2f(v1[7]);
    atomicAdd(agg + (size_t)dst * 64 + o, acc);
}

// ---- C (fused C1+C2, MFMA): per 64-node block:
// phase1: acc1 = x @ [root | w_hh^T]  (16 col-tiles)
//   m = relu(acc1[0..3] + agg + conv_b) -> LDS ; gh = acc1[4..15] + b_hh (regs)
// phase2: acc2 = m @ w_ih^T (12 col-tiles); gates lane-local; hout (in-place ok)
__global__ __launch_bounds__(256) void k_C(
        const float* __restrict__ x, const float* __restrict__ agg,
        const u16* __restrict__ w1hi, const u16* __restrict__ w1lo,
        const u16* __restrict__ w2hi, const u16* __restrict__ w2lo,
        const float* __restrict__ conv_b, const float* __restrict__ b_hh,
        const float* __restrict__ b_ih, float* __restrict__ hout, int N) {
    __shared__ __align__(16) u16 wb_hi[16 * 512];
    __shared__ __align__(16) u16 wb_lo[16 * 512];
    __shared__ float mld[4][16][68];   // padded: stride 68 -> <=2-way bank conflicts
    int t = threadIdx.x, l = t & 63, w = t >> 6, g = l >> 4;
    int n0 = blockIdx.x * 64 + w * 16;
    int node = n0 + (l & 15);
    int nc = node < N ? node : N - 1;
    const float* xrow = x + (size_t)nc * 64 + g * 8;

    // x fragments (B operand), split hi/lo
    s8v xhi[2], xlo[2];
    #pragma unroll
    for (int kc = 0; kc < 2; kc++) {
        f32x4 a = *(const f32x4*)(xrow + kc * 32);
        f32x4 b = *(const f32x4*)(xrow + kc * 32 + 4);
        #pragma unroll
        for (int j = 0; j < 8; j++) {
            float v = j < 4 ? a[j] : b[j - 4];
            u16 h = f2b(v);
            xhi[kc][j] = (short)h;
            xlo[kc][j] = (short)f2b(v - b2f(h));
        }
    }

    f32x4 acc1[16];
    #pragma unroll
    for (int ct = 0; ct < 16; ct++) acc1[ct] = (f32x4)(0.f);

    for (int kc = 0; kc < 2; kc++) {
        if (kc) __syncthreads();
        const uint4* ghp = (const uint4*)(w1hi + kc * 16 * 512);
        const uint4* glp = (const uint4*)(w1lo + kc * 16 * 512);
        uint4* lh = (uint4*)wb_hi;
        uint4* ll = (uint4*)wb_lo;
        for (int i = t; i < 1024; i += 256) { lh[i] = ghp[i]; ll[i] = glp[i]; }
        __syncthreads();
        #pragma unroll
        for (int ct = 0; ct < 16; ct++) {
            s8v whi = *(const s8v*)(wb_hi + ct * 512 + l * 8);
            s8v wlo = *(const s8v*)(wb_lo + ct * 512 + l * 8);
            acc1[ct] = __builtin_amdgcn_mfma_f32_16x16x32_bf16(whi, xhi[kc], acc1[ct], 0, 0, 0);
            acc1[ct] = __builtin_amdgcn_mfma_f32_16x16x32_bf16(wlo, xhi[kc], acc1[ct], 0, 0, 0);
            acc1[ct] = __builtin_amdgcn_mfma_f32_16x16x32_bf16(whi, xlo[kc], acc1[ct], 0, 0, 0);
        }
    }

    // epilogue 1: m -> LDS ; gh = acc1[4..15] + b_hh (in place)
    #pragma unroll
    for (int ct = 0; ct < 4; ct++) {
        int c = ct * 16 + g * 4;
        f32x4 av = (f32x4)(0.f);
        if (node < N) av = *(const f32x4*)(agg + (size_t)node * 64 + c);
        f32x4 cb = *(const f32x4*)(conv_b + c);
        f32x4 mv;
        #pragma unroll
        for (int r = 0; r < 4; r++) mv[r] = fmaxf(acc1[ct][r] + av[r] + cb[r], 0.f);
        *(f32x4*)(&mld[w][l & 15][c]) = mv;
    }
    #pragma unroll
    for (int ct = 4; ct < 16; ct++) {
        int c = (ct - 4) * 16 + g * 4;
        f32x4 bh = *(const f32x4*)(b_hh + c);
        #pragma unroll
        for (int r = 0; r < 4; r++) acc1[ct][r] += bh[r];
    }
    __syncthreads();

    // m fragments from LDS, split hi/lo
    s8v mhi[2], mlo[2];
    #pragma unroll
    for (int kc = 0; kc < 2; kc++) {
        const float* mr = &mld[w][l & 15][kc * 32 + g * 8];
        f32x4 a = *(const f32x4*)(mr);
        f32x4 b = *(const f32x4*)(mr + 4);
        #pragma unroll
        for (int j = 0; j < 8; j++) {
            float v = j < 4 ? a[j] : b[j - 4];
            u16 h = f2b(v);
            mhi[kc][j] = (short)h;
            mlo[kc][j] = (short)f2b(v - b2f(h));
        }
    }

    f32x4 acc2[12];
    #pragma unroll
    for (int ct = 0; ct < 12; ct++) acc2[ct] = (f32x4)(0.f);

    for (int kc = 0; kc < 2; kc++) {
        __syncthreads();   // protect wb reuse (after phase1 compute / kc0 compute)
        const uint4* ghp = (const uint4*)(w2hi + kc * 12 * 512);
        const uint4* glp = (const uint4*)(w2lo + kc * 12 * 512);
        uint4* lh = (uint4*)wb_hi;
        uint4* ll = (uint4*)wb_lo;
        for (int i = t; i < 768; i += 256) { lh[i] = ghp[i]; ll[i] = glp[i]; }
        __syncthreads();
        #pragma unroll
        for (int ct = 0; ct < 12; ct++) {
            s8v whi = *(const s8v*)(wb_hi + ct * 512 + l * 8);
            s8v wlo = *(const s8v*)(wb_lo + ct * 512 + l * 8);
            acc2[ct] = __builtin_amdgcn_mfma_f32_16x16x32_bf16(whi, mhi[kc], acc2[ct], 0, 0, 0);
            acc2[ct] = __builtin_amdgcn_mfma_f32_16x16x32_bf16(wlo, mhi[kc], acc2[ct], 0, 0, 0);
            acc2[ct] = __builtin_amdgcn_mfma_f32_16x16x32_bf16(whi, mlo[kc], acc2[ct], 0, 0, 0);
        }
    }

    // epilogue 2: gates. gi col c=q*16+g*4+r: r-gate acc2[q], z acc2[4+q], n acc2[8+q];
    // gh: r acc1[4+q], z acc1[8+q], n acc1[12+q]. All lane-local.
    #pragma unroll
    for (int q = 0; q < 4; q++) {
        int c = q * 16 + g * 4;
        f32x4 bir = *(const f32x4*)(b_ih + c);
        f32x4 biz = *(const f32x4*)(b_ih + 64 + c);
        f32x4 bin = *(const f32x4*)(b_ih + 128 + c);
        f32x4 hv = (f32x4)(0.f);
        if (node < N) hv = *(const f32x4*)(x + (size_t)node * 64 + c);
        f32x4 outv;
        #pragma unroll
        for (int r = 0; r < 4; r++) {
            float rr = sigm(acc2[q][r] + bir[r] + acc1[4 + q][r]);
            float zz = sigm(acc2[4 + q][r] + biz[r] + acc1[8 + q][r]);
            float nt = tanh_f(acc2[8 + q][r] + bin[r] + rr * acc1[12 + q][r]);
            outv[r] = (1.f - zz) * nt + zz * hv[r];
        }
        if (node < N) *(f32x4*)(hout + (size_t)node * 64 + c) = outv;
    }
}

extern "C" void kernel_launch(void* const* d_in, const int* in_sizes, int n_in,
                              void* d_out, int out_size, void* d_ws, size_t ws_size,
                              hipStream_t stream) {
    const float* x_in   = (const float*)d_in[0];
    const int*   ei     = (const int*)d_in[1];
    const float* ea     = (const float*)d_in[2];
    const float* lin0_w = (const float*)d_in[3];
    const float* lin0_b = (const float*)d_in[4];
    const float* nn_w   = (const float*)d_in[5];
    const float* nn_b   = (const float*)d_in[6];
    const float* root   = (const float*)d_in[7];
    const float* conv_b = (const float*)d_in[8];
    const float* w_ih   = (const float*)d_in[9];
    const float* w_hh   = (const float*)d_in[10];
    const float* b_ih   = (const float*)d_in[11];
    const float* b_hh   = (const float*)d_in[12];

    int N = in_sizes[0] / 32;
    int E = in_sizes[1] / 2;

    char* ws = (char*)d_ws;
    size_t off = 0;
    auto alloc = [&](size_t bytes) { char* p = ws + off; off += (bytes + 255) & ~(size_t)255; return p; };
    float* xbuf = (float*)alloc((size_t)N * 64 * 4);
    float* agg  = (float*)alloc((size_t)N * 64 * 4);
    u16*   Tbuf = (u16*)alloc((size_t)N * TW * 2);
    u16*   wfhi = (u16*)alloc((size_t)2 * 68 * 64 * 8 * 2);
    u16*   wflo = (u16*)alloc((size_t)2 * 68 * 64 * 8 * 2);
    u16*   w1hi = (u16*)alloc(16384 * 2);
    u16*   w1lo = (u16*)alloc(16384 * 2);
    u16*   w2hi = (u16*)alloc(12288 * 2);
    u16*   w2lo = (u16*)alloc(12288 * 2);
    (void)ws_size;

    hipLaunchKernelGGL(k_prepW, dim3(272), dim3(256), 0, stream, nn_w, nn_b, wfhi, wflo);
    hipLaunchKernelGGL(k_prepW12, dim3(112), dim3(256), 0, stream, root, w_hh, w_ih, w1hi, w1lo, w2hi, w2lo);
    hipLaunchKernelGGL(k_lin0, dim3((N + 3) / 4), dim3(256), 0, stream, x_in, lin0_w, lin0_b, xbuf, N);

    for (int it = 0; it < 3; it++) {
        hipLaunchKernelGGL(k_A_mfma, dim3((N + 63) / 64, 4), dim3(256), 0, stream, xbuf, wfhi, wflo, Tbuf, N);
        hipMemsetAsync(agg, 0, (size_t)N * 64 * 4, stream);
        hipLaunchKernelGGL(k_B, dim3((E * 64 + 255) / 256), dim3(256), 0, stream, Tbuf, ei, ea, agg, E);
        float* hout = (it == 2) ? (float*)d_out : xbuf;
        hipLaunchKernelGGL(k_C, dim3((N + 63) / 64), dim3(256), 0, stream, xbuf, agg,
                           w1hi, w1lo, w2hi, w2lo, conv_b, b_hh, b_ih, hout, N);
    }
}

// Round 4
// 384.039 us; speedup vs baseline: 2.5007x; 1.0963x over previous
//
#include <hip/hip_runtime.h>
#include <hip/hip_bf16.h>

typedef unsigned short u16;
typedef __attribute__((ext_vector_type(8))) unsigned short us8;
typedef __attribute__((ext_vector_type(8))) _Float16 h8v;   // MFMA f16 A/B frag (4 VGPR)
typedef __attribute__((ext_vector_type(4))) float f32x4;    // MFMA C/D frag

#define TW 1088  // T row width: 64*16 (T) + 64 (bias term)

static __device__ __forceinline__ u16 f2h(float f) {
    _Float16 h = (_Float16)f;          // RNE
    u16 r; __builtin_memcpy(&r, &h, 2); return r;
}
static __device__ __forceinline__ float h2f(u16 b) {
    _Float16 h; __builtin_memcpy(&h, &b, 2); return (float)h;
}
static __device__ __forceinline__ float sigm(float x) {
    return 1.f / (1.f + __expf(-x));
}
static __device__ __forceinline__ float tanh_f(float x) {
    return 1.f - 2.f / (__expf(2.f * x) + 1.f);
}

// ---- one-time: pack W' = [nn_w | nn_b-as-matrix] ([64 k][1088 col]) into MFMA
// A-frag layout, fp16. idx=((kc*68+ct)*64+lane)*8+j ; k=kc*32+(lane>>4)*8+j ;
// col=ct*16+(lane&15)
__global__ __launch_bounds__(256) void k_prepW(
        const float* __restrict__ nn_w, const float* __restrict__ nn_b,
        u16* __restrict__ wf) {
    int idx = blockIdx.x * 256 + threadIdx.x;
    if (idx >= 2 * 68 * 64 * 8) return;
    int j = idx & 7, lane = (idx >> 3) & 63;
    int rest = idx >> 9;
    int ct = rest % 68, kc = rest / 68;
    int k = kc * 32 + ((lane >> 4) * 8) + j;
    int col = ct * 16 + (lane & 15);
    float v = (col < 1024) ? nn_w[(size_t)k * 1024 + col]
                           : nn_b[(size_t)k * 64 + (col - 1024)];
    wf[idx] = f2h(v);
}

// ---- one-time: pack W1=[root | w_hh^T] ([64 k][256 col], 16 ct) and
// W2=w_ih^T ([64 k][192 col], 12 ct) into MFMA A-frag layout, fp16.
__global__ __launch_bounds__(256) void k_prepW12(
        const float* __restrict__ root, const float* __restrict__ w_hh,
        const float* __restrict__ w_ih, u16* __restrict__ w1, u16* __restrict__ w2) {
    int idx = blockIdx.x * 256 + threadIdx.x;
    if (idx < 16384) {
        int j = idx & 7, lane = (idx >> 3) & 63;
        int rest = idx >> 9;          // kc*16 + ct
        int ct = rest & 15, kc = rest >> 4;
        int k = kc * 32 + ((lane >> 4) * 8) + j;
        int col = ct * 16 + (lane & 15);
        float v = (col < 64) ? root[(size_t)k * 64 + col]
                             : w_hh[(size_t)(col - 64) * 64 + k];
        w1[idx] = f2h(v);
    } else if (idx < 16384 + 12288) {
        int i2 = idx - 16384;
        int j = i2 & 7, lane = (i2 >> 3) & 63;
        int rest = i2 >> 9;           // kc*12 + ct
        int ct = rest % 12, kc = rest / 12;
        int k = kc * 32 + ((lane >> 4) * 8) + j;
        int col = ct * 16 + (lane & 15);
        w2[i2] = f2h(w_ih[(size_t)col * 64 + k]);
    }
}

// ---- lin0: out = relu(x[N,32] @ w[64,32]^T + b)
__global__ __launch_bounds__(256) void k_lin0(
        const float* __restrict__ x, const float* __restrict__ w,
        const float* __restrict__ b, float* __restrict__ out, int N) {
    __shared__ float xs[4][32];
    int n0 = blockIdx.x * 4;
    int t = threadIdx.x;
    if (t < 128) {
        int n = n0 + (t >> 5);
        if (n < N) xs[t >> 5][t & 31] = x[(size_t)n * 32 + (t & 31)];
    }
    __syncthreads();
    int c = t & 63, g = t >> 6;
    int n = n0 + g;
    if (n < N) {
        float acc = b[c];
        #pragma unroll
        for (int i = 0; i < 32; i++) acc += xs[g][i] * w[c * 32 + i];
        out[(size_t)n * 64 + c] = fmaxf(acc, 0.f);
    }
}

// ---- A (MFMA fp16): T[n,col] = sum_k x[n,k]*W'[k,col], fp16 in/out, fp32 acc.
// Block: 4 waves x 16 nodes = 64 nodes, 17 col-tiles (grid.y=4 covers 68).
__global__ __launch_bounds__(256) void k_A_mfma(
        const float* __restrict__ X, const u16* __restrict__ wf,
        u16* __restrict__ T, int N) {
    __shared__ __align__(16) u16 lw[17 * 512];
    int t = threadIdx.x;
    int l = t & 63, w = t >> 6;
    int n0 = blockIdx.x * 64 + w * 16;
    int ct0 = blockIdx.y * 17;
    int node = n0 + (l & 15);
    int nload = node < N ? node : N - 1;
    const float* xrow = X + (size_t)nload * 64 + ((l >> 4) * 8);

    f32x4 acc[17];
    #pragma unroll
    for (int ct = 0; ct < 17; ct++) acc[ct] = (f32x4)(0.f);

    for (int kc = 0; kc < 2; kc++) {
        if (kc) __syncthreads();  // phase-0 compute done before LDS overwrite
        const uint4* gh = (const uint4*)(wf + (size_t)(kc * 68 + ct0) * 512);
        uint4* lh = (uint4*)lw;
        for (int i = t; i < 17 * 512 / 8; i += 256) lh[i] = gh[i];
        __syncthreads();

        // X fragment (B operand): lane -> node = n0+(l&15), k = kc*32+(l>>4)*8+j
        float4 xa = *(const float4*)(xrow + kc * 32);
        float4 xb = *(const float4*)(xrow + kc * 32 + 4);
        h8v xh;
        xh[0] = (_Float16)xa.x; xh[1] = (_Float16)xa.y;
        xh[2] = (_Float16)xa.z; xh[3] = (_Float16)xa.w;
        xh[4] = (_Float16)xb.x; xh[5] = (_Float16)xb.y;
        xh[6] = (_Float16)xb.z; xh[7] = (_Float16)xb.w;
        #pragma unroll
        for (int ct = 0; ct < 17; ct++) {
            h8v wh = *(const h8v*)(lw + ct * 512 + l * 8);
            acc[ct] = __builtin_amdgcn_mfma_f32_16x16x32_f16(wh, xh, acc[ct], 0, 0, 0);
        }
    }

    // D: col(lane&15)=node, row((lane>>4)*4+reg)=W-col -> 4 consecutive T cols/lane
    if (node < N) {
        int g = l >> 4;
        u16* trow = T + (size_t)node * TW;
        #pragma unroll
        for (int ct = 0; ct < 17; ct++) {
            ushort4 pk;
            pk.x = f2h(acc[ct][0]);
            pk.y = f2h(acc[ct][1]);
            pk.z = f2h(acc[ct][2]);
            pk.w = f2h(acc[ct][3]);
            *(ushort4*)(trow + (ct0 + ct) * 16 + g * 4) = pk;
        }
    }
}

// ---- B: per-edge msg + scatter. 1 wave per edge, lane o in [0,64)
__global__ __launch_bounds__(256) void k_B(
        const u16* __restrict__ T, const int* __restrict__ ei,
        const float* __restrict__ ea, float* __restrict__ agg, int E) {
    int gid = blockIdx.x * 256 + threadIdx.x;
    int e = gid >> 6, o = gid & 63;
    if (e >= E) return;
    int src = ei[e], dst = ei[E + e];
    const float4* ea4 = (const float4*)(ea + (size_t)e * 16);
    float4 a0 = ea4[0], a1 = ea4[1], a2 = ea4[2], a3 = ea4[3];
    const u16* Tr = T + (size_t)src * TW;
    us8 v0 = *(const us8*)(Tr + o * 16);
    us8 v1 = *(const us8*)(Tr + o * 16 + 8);
    float acc = h2f(Tr[1024 + o]);
    acc += a0.x * h2f(v0[0]) + a0.y * h2f(v0[1]) + a0.z * h2f(v0[2]) + a0.w * h2f(v0[3]);
    acc += a1.x * h2f(v0[4]) + a1.y * h2f(v0[5]) + a1.z * h2f(v0[6]) + a1.w * h2f(v0[7]);
    acc += a2.x * h2f(v1[0]) + a2.y * h2f(v1[1]) + a2.z * h2f(v1[2]) + a2.w * h2f(v1[3]);
    acc += a3.x * h2f(v1[4]) + a3.y * h2f(v1[5]) + a3.z * h2f(v1[6]) + a3.w * h2f(v1[7]);
    atomicAdd(agg + (size_t)dst * 64 + o, acc);
}

// ---- C (fused C1+C2, MFMA fp16): per 64-node block:
// phase1: acc1 = x @ [root | w_hh^T]  (16 col-tiles)
//   m = relu(acc1[0..3] + agg + conv_b) -> LDS ; gh = acc1[4..15] + b_hh (regs)
// phase2: acc2 = m @ w_ih^T (12 col-tiles); gates lane-local; hout (in-place ok)
__global__ __launch_bounds__(256) void k_C(
        const float* __restrict__ x, const float* __restrict__ agg,
        const u16* __restrict__ w1, const u16* __restrict__ w2,
        const float* __restrict__ conv_b, const float* __restrict__ b_hh,
        const float* __restrict__ b_ih, float* __restrict__ hout, int N) {
    __shared__ __align__(16) u16 wb[16 * 512];
    __shared__ float mld[4][16][68];   // padded: stride 68 -> <=2-way bank conflicts
    int t = threadIdx.x, l = t & 63, w = t >> 6, g = l >> 4;
    int n0 = blockIdx.x * 64 + w * 16;
    int node = n0 + (l & 15);
    int nc = node < N ? node : N - 1;
    const float* xrow = x + (size_t)nc * 64 + g * 8;

    // x fragments (B operand), fp16
    h8v xh[2];
    #pragma unroll
    for (int kc = 0; kc < 2; kc++) {
        f32x4 a = *(const f32x4*)(xrow + kc * 32);
        f32x4 b = *(const f32x4*)(xrow + kc * 32 + 4);
        #pragma unroll
        for (int j = 0; j < 8; j++) xh[kc][j] = (_Float16)(j < 4 ? a[j] : b[j - 4]);
    }

    f32x4 acc1[16];
    #pragma unroll
    for (int ct = 0; ct < 16; ct++) acc1[ct] = (f32x4)(0.f);

    for (int kc = 0; kc < 2; kc++) {
        if (kc) __syncthreads();
        const uint4* ghp = (const uint4*)(w1 + kc * 16 * 512);
        uint4* lh = (uint4*)wb;
        for (int i = t; i < 1024; i += 256) lh[i] = ghp[i];
        __syncthreads();
        #pragma unroll
        for (int ct = 0; ct < 16; ct++) {
            h8v wh = *(const h8v*)(wb + ct * 512 + l * 8);
            acc1[ct] = __builtin_amdgcn_mfma_f32_16x16x32_f16(wh, xh[kc], acc1[ct], 0, 0, 0);
        }
    }

    // epilogue 1: m -> LDS ; gh = acc1[4..15] + b_hh (in place)
    #pragma unroll
    for (int ct = 0; ct < 4; ct++) {
        int c = ct * 16 + g * 4;
        f32x4 av = (f32x4)(0.f);
        if (node < N) av = *(const f32x4*)(agg + (size_t)node * 64 + c);
        f32x4 cb = *(const f32x4*)(conv_b + c);
        f32x4 mv;
        #pragma unroll
        for (int r = 0; r < 4; r++) mv[r] = fmaxf(acc1[ct][r] + av[r] + cb[r], 0.f);
        *(f32x4*)(&mld[w][l & 15][c]) = mv;
    }
    #pragma unroll
    for (int ct = 4; ct < 16; ct++) {
        int c = (ct - 4) * 16 + g * 4;
        f32x4 bh = *(const f32x4*)(b_hh + c);
        #pragma unroll
        for (int r = 0; r < 4; r++) acc1[ct][r] += bh[r];
    }
    __syncthreads();

    // m fragments from LDS, fp16
    h8v mh[2];
    #pragma unroll
    for (int kc = 0; kc < 2; kc++) {
        const float* mr = &mld[w][l & 15][kc * 32 + g * 8];
        f32x4 a = *(const f32x4*)(mr);
        f32x4 b = *(const f32x4*)(mr + 4);
        #pragma unroll
        for (int j = 0; j < 8; j++) mh[kc][j] = (_Float16)(j < 4 ? a[j] : b[j - 4]);
    }

    f32x4 acc2[12];
    #pragma unroll
    for (int ct = 0; ct < 12; ct++) acc2[ct] = (f32x4)(0.f);

    for (int kc = 0; kc < 2; kc++) {
        __syncthreads();   // protect wb reuse
        const uint4* ghp = (const uint4*)(w2 + kc * 12 * 512);
        uint4* lh = (uint4*)wb;
        for (int i = t; i < 768; i += 256) lh[i] = ghp[i];
        __syncthreads();
        #pragma unroll
        for (int ct = 0; ct < 12; ct++) {
            h8v wh = *(const h8v*)(wb + ct * 512 + l * 8);
            acc2[ct] = __builtin_amdgcn_mfma_f32_16x16x32_f16(wh, mh[kc], acc2[ct], 0, 0, 0);
        }
    }

    // epilogue 2: gates. gi col c=q*16+g*4+r: r acc2[q], z acc2[4+q], n acc2[8+q];
    // gh: r acc1[4+q], z acc1[8+q], n acc1[12+q]. All lane-local.
    #pragma unroll
    for (int q = 0; q < 4; q++) {
        int c = q * 16 + g * 4;
        f32x4 bir = *(const f32x4*)(b_ih + c);
        f32x4 biz = *(const f32x4*)(b_ih + 64 + c);
        f32x4 bin = *(const f32x4*)(b_ih + 128 + c);
        f32x4 hv = (f32x4)(0.f);
        if (node < N) hv = *(const f32x4*)(x + (size_t)node * 64 + c);
        f32x4 outv;
        #pragma unroll
        for (int r = 0; r < 4; r++) {
            float rr = sigm(acc2[q][r] + bir[r] + acc1[4 + q][r]);
            float zz = sigm(acc2[4 + q][r] + biz[r] + acc1[8 + q][r]);
            float nt = tanh_f(acc2[8 + q][r] + bin[r] + rr * acc1[12 + q][r]);
            outv[r] = (1.f - zz) * nt + zz * hv[r];
        }
        if (node < N) *(f32x4*)(hout + (size_t)node * 64 + c) = outv;
    }
}

extern "C" void kernel_launch(void* const* d_in, const int* in_sizes, int n_in,
                              void* d_out, int out_size, void* d_ws, size_t ws_size,
                              hipStream_t stream) {
    const float* x_in   = (const float*)d_in[0];
    const int*   ei     = (const int*)d_in[1];
    const float* ea     = (const float*)d_in[2];
    const float* lin0_w = (const float*)d_in[3];
    const float* lin0_b = (const float*)d_in[4];
    const float* nn_w   = (const float*)d_in[5];
    const float* nn_b   = (const float*)d_in[6];
    const float* root   = (const float*)d_in[7];
    const float* conv_b = (const float*)d_in[8];
    const float* w_ih   = (const float*)d_in[9];
    const float* w_hh   = (const float*)d_in[10];
    const float* b_ih   = (const float*)d_in[11];
    const float* b_hh   = (const float*)d_in[12];

    int N = in_sizes[0] / 32;
    int E = in_sizes[1] / 2;

    char* ws = (char*)d_ws;
    size_t off = 0;
    auto alloc = [&](size_t bytes) { char* p = ws + off; off += (bytes + 255) & ~(size_t)255; return p; };
    float* xbuf = (float*)alloc((size_t)N * 64 * 4);
    float* agg  = (float*)alloc((size_t)N * 64 * 4);
    u16*   Tbuf = (u16*)alloc((size_t)N * TW * 2);
    u16*   wf   = (u16*)alloc((size_t)2 * 68 * 64 * 8 * 2);
    u16*   w1   = (u16*)alloc(16384 * 2);
    u16*   w2   = (u16*)alloc(12288 * 2);
    (void)ws_size;

    hipLaunchKernelGGL(k_prepW, dim3(272), dim3(256), 0, stream, nn_w, nn_b, wf);
    hipLaunchKernelGGL(k_prepW12, dim3(112), dim3(256), 0, stream, root, w_hh, w_ih, w1, w2);
    hipLaunchKernelGGL(k_lin0, dim3((N + 3) / 4), dim3(256), 0, stream, x_in, lin0_w, lin0_b, xbuf, N);

    for (int it = 0; it < 3; it++) {
        hipLaunchKernelGGL(k_A_mfma, dim3((N + 63) / 64, 4), dim3(256), 0, stream, xbuf, wf, Tbuf, N);
        hipMemsetAsync(agg, 0, (size_t)N * 64 * 4, stream);
        hipLaunchKernelGGL(k_B, dim3((E * 64 + 255) / 256), dim3(256), 0, stream, Tbuf, ei, ea, agg, E);
        float* hout = (it == 2) ? (float*)d_out : xbuf;
        hipLaunchKernelGGL(k_C, dim3((N + 63) / 64), dim3(256), 0, stream, xbuf, agg,
                           w1, w2, conv_b, b_hh, b_ih, hout, N);
    }
}

// Round 5
// 340.469 us; speedup vs baseline: 2.8207x; 1.1280x over previous
//
#include <hip/hip_runtime.h>
#include <hip/hip_bf16.h>

typedef unsigned short u16;
typedef __attribute__((ext_vector_type(8))) unsigned short us8;
typedef __attribute__((ext_vector_type(8))) _Float16 h8v;   // MFMA f16 A/B frag (4 VGPR)
typedef __attribute__((ext_vector_type(4))) float f32x4;    // MFMA C/D frag

#define TW 1088  // T row width: 64*16 (T) + 64 (bias term)

static __device__ __forceinline__ u16 f2h(float f) {
    _Float16 h = (_Float16)f;          // RNE
    u16 r; __builtin_memcpy(&r, &h, 2); return r;
}
static __device__ __forceinline__ float h2f(u16 b) {
    _Float16 h; __builtin_memcpy(&h, &b, 2); return (float)h;
}
static __device__ __forceinline__ float sigm(float x) {
    return 1.f / (1.f + __expf(-x));
}
static __device__ __forceinline__ float tanh_f(float x) {
    return 1.f - 2.f / (__expf(2.f * x) + 1.f);
}

// ---- one-time: pack W' = [nn_w | nn_b-as-matrix] ([64 k][1088 col]) into MFMA
// A-frag layout, fp16. idx=((kc*68+ct)*64+lane)*8+j ; k=kc*32+(lane>>4)*8+j ;
// col=ct*16+(lane&15)
__global__ __launch_bounds__(256) void k_prepW(
        const float* __restrict__ nn_w, const float* __restrict__ nn_b,
        u16* __restrict__ wf) {
    int idx = blockIdx.x * 256 + threadIdx.x;
    if (idx >= 2 * 68 * 64 * 8) return;
    int j = idx & 7, lane = (idx >> 3) & 63;
    int rest = idx >> 9;
    int ct = rest % 68, kc = rest / 68;
    int k = kc * 32 + ((lane >> 4) * 8) + j;
    int col = ct * 16 + (lane & 15);
    float v = (col < 1024) ? nn_w[(size_t)k * 1024 + col]
                           : nn_b[(size_t)k * 64 + (col - 1024)];
    wf[idx] = f2h(v);
}

// ---- one-time: pack W1=[root | w_hh^T] (16 ct), W2=w_ih^T (12 ct), and
// W0=lin0_w^T ([32 k][64 col], 4 ct, single K-chunk) into MFMA A-frag fp16.
__global__ __launch_bounds__(256) void k_prepW12(
        const float* __restrict__ root, const float* __restrict__ w_hh,
        const float* __restrict__ w_ih, const float* __restrict__ lin0_w,
        u16* __restrict__ w1, u16* __restrict__ w2, u16* __restrict__ w0) {
    int idx = blockIdx.x * 256 + threadIdx.x;
    if (idx < 16384) {
        int j = idx & 7, lane = (idx >> 3) & 63;
        int rest = idx >> 9;          // kc*16 + ct
        int ct = rest & 15, kc = rest >> 4;
        int k = kc * 32 + ((lane >> 4) * 8) + j;
        int col = ct * 16 + (lane & 15);
        float v = (col < 64) ? root[(size_t)k * 64 + col]
                             : w_hh[(size_t)(col - 64) * 64 + k];
        w1[idx] = f2h(v);
    } else if (idx < 16384 + 12288) {
        int i2 = idx - 16384;
        int j = i2 & 7, lane = (i2 >> 3) & 63;
        int rest = i2 >> 9;           // kc*12 + ct
        int ct = rest % 12, kc = rest / 12;
        int k = kc * 32 + ((lane >> 4) * 8) + j;
        int col = ct * 16 + (lane & 15);
        w2[i2] = f2h(w_ih[(size_t)col * 64 + k]);
    } else if (idx < 16384 + 12288 + 2048) {
        int i3 = idx - 16384 - 12288;
        int j = i3 & 7, lane = (i3 >> 3) & 63;
        int ct = i3 >> 9;             // 0..3
        int k = ((lane >> 4) * 8) + j;           // 0..31
        int col = ct * 16 + (lane & 15);         // 0..63
        w0[i3] = f2h(lin0_w[(size_t)col * 32 + k]);  // lin0_w is [64 out][32 in]
    }
}

// ---- lin0 (MFMA fp16): out = relu(x[N,32] @ w0 + b). 64 nodes/block, 4 waves,
// single K=32 chunk, 4 col-tiles. Weight frags read direct from global (L2-hot).
__global__ __launch_bounds__(256) void k_lin0(
        const float* __restrict__ x, const u16* __restrict__ w0,
        const float* __restrict__ b, float* __restrict__ out, int N) {
    int t = threadIdx.x, l = t & 63, w = t >> 6, g = l >> 4;
    int n0 = blockIdx.x * 64 + w * 16;
    int node = n0 + (l & 15);
    int nc = node < N ? node : N - 1;
    const float* xrow = x + (size_t)nc * 32 + g * 8;
    float4 xa = *(const float4*)(xrow);
    float4 xb = *(const float4*)(xrow + 4);
    h8v xh;
    xh[0] = (_Float16)xa.x; xh[1] = (_Float16)xa.y;
    xh[2] = (_Float16)xa.z; xh[3] = (_Float16)xa.w;
    xh[4] = (_Float16)xb.x; xh[5] = (_Float16)xb.y;
    xh[6] = (_Float16)xb.z; xh[7] = (_Float16)xb.w;

    f32x4 acc[4];
    #pragma unroll
    for (int ct = 0; ct < 4; ct++) {
        h8v wh = *(const h8v*)(w0 + (ct * 64 + l) * 8);
        acc[ct] = __builtin_amdgcn_mfma_f32_16x16x32_f16(wh, xh, (f32x4)(0.f), 0, 0, 0);
    }
    if (node < N) {
        #pragma unroll
        for (int ct = 0; ct < 4; ct++) {
            int c = ct * 16 + g * 4;
            f32x4 bb = *(const f32x4*)(b + c);
            f32x4 ov;
            #pragma unroll
            for (int r = 0; r < 4; r++) ov[r] = fmaxf(acc[ct][r] + bb[r], 0.f);
            *(f32x4*)(out + (size_t)node * 64 + c) = ov;
        }
    }
}

// ---- A (MFMA fp16): T[n,col] = sum_k x[n,k]*W'[k,col], fp16 in/out, fp32 acc.
// Block: 4 waves x 16 nodes = 64 nodes, 17 col-tiles (grid.y=4 covers 68).
__global__ __launch_bounds__(256) void k_A_mfma(
        const float* __restrict__ X, const u16* __restrict__ wf,
        u16* __restrict__ T, int N) {
    __shared__ __align__(16) u16 lw[17 * 512];
    int t = threadIdx.x;
    int l = t & 63, w = t >> 6;
    int n0 = blockIdx.x * 64 + w * 16;
    int ct0 = blockIdx.y * 17;
    int node = n0 + (l & 15);
    int nload = node < N ? node : N - 1;
    const float* xrow = X + (size_t)nload * 64 + ((l >> 4) * 8);

    f32x4 acc[17];
    #pragma unroll
    for (int ct = 0; ct < 17; ct++) acc[ct] = (f32x4)(0.f);

    for (int kc = 0; kc < 2; kc++) {
        if (kc) __syncthreads();  // phase-0 compute done before LDS overwrite
        const uint4* gh = (const uint4*)(wf + (size_t)(kc * 68 + ct0) * 512);
        uint4* lh = (uint4*)lw;
        for (int i = t; i < 17 * 512 / 8; i += 256) lh[i] = gh[i];
        __syncthreads();

        // X fragment (B operand): lane -> node = n0+(l&15), k = kc*32+(l>>4)*8+j
        float4 xa = *(const float4*)(xrow + kc * 32);
        float4 xb = *(const float4*)(xrow + kc * 32 + 4);
        h8v xh;
        xh[0] = (_Float16)xa.x; xh[1] = (_Float16)xa.y;
        xh[2] = (_Float16)xa.z; xh[3] = (_Float16)xa.w;
        xh[4] = (_Float16)xb.x; xh[5] = (_Float16)xb.y;
        xh[6] = (_Float16)xb.z; xh[7] = (_Float16)xb.w;
        #pragma unroll
        for (int ct = 0; ct < 17; ct++) {
            h8v wh = *(const h8v*)(lw + ct * 512 + l * 8);
            acc[ct] = __builtin_amdgcn_mfma_f32_16x16x32_f16(wh, xh, acc[ct], 0, 0, 0);
        }
    }

    // D: col(lane&15)=node, row((lane>>4)*4+reg)=W-col -> 4 consecutive T cols/lane
    if (node < N) {
        int g = l >> 4;
        u16* trow = T + (size_t)node * TW;
        #pragma unroll
        for (int ct = 0; ct < 17; ct++) {
            ushort4 pk;
            pk.x = f2h(acc[ct][0]);
            pk.y = f2h(acc[ct][1]);
            pk.z = f2h(acc[ct][2]);
            pk.w = f2h(acc[ct][3]);
            *(ushort4*)(trow + (ct0 + ct) * 16 + g * 4) = pk;
        }
    }
}

// ---- B: per-edge msg + scatter. 1 wave per edge, lane o in [0,64)
__global__ __launch_bounds__(256) void k_B(
        const u16* __restrict__ T, const int* __restrict__ ei,
        const float* __restrict__ ea, float* __restrict__ agg, int E) {
    int gid = blockIdx.x * 256 + threadIdx.x;
    int e = gid >> 6, o = gid & 63;
    if (e >= E) return;
    int src = ei[e], dst = ei[E + e];
    const float4* ea4 = (const float4*)(ea + (size_t)e * 16);
    float4 a0 = ea4[0], a1 = ea4[1], a2 = ea4[2], a3 = ea4[3];
    const u16* Tr = T + (size_t)src * TW;
    us8 v0 = *(const us8*)(Tr + o * 16);
    us8 v1 = *(const us8*)(Tr + o * 16 + 8);
    float acc = h2f(Tr[1024 + o]);
    acc += a0.x * h2f(v0[0]) + a0.y * h2f(v0[1]) + a0.z * h2f(v0[2]) + a0.w * h2f(v0[3]);
    acc += a1.x * h2f(v0[4]) + a1.y * h2f(v0[5]) + a1.z * h2f(v0[6]) + a1.w * h2f(v0[7]);
    acc += a2.x * h2f(v1[0]) + a2.y * h2f(v1[1]) + a2.z * h2f(v1[2]) + a2.w * h2f(v1[3]);
    acc += a3.x * h2f(v1[4]) + a3.y * h2f(v1[5]) + a3.z * h2f(v1[6]) + a3.w * h2f(v1[7]);
    atomicAdd(agg + (size_t)dst * 64 + o, acc);
}

// ---- C (fused C1+C2, MFMA fp16): per 64-node block:
// phase1: acc1 = x @ [root | w_hh^T]  (16 col-tiles)
//   m = relu(acc1[0..3] + agg + conv_b) -> LDS ; gh = acc1[4..15] + b_hh (regs)
// phase2: acc2 = m @ w_ih^T (12 col-tiles); gates lane-local; hout (in-place ok)
__global__ __launch_bounds__(256) void k_C(
        const float* __restrict__ x, const float* __restrict__ agg,
        const u16* __restrict__ w1, const u16* __restrict__ w2,
        const float* __restrict__ conv_b, const float* __restrict__ b_hh,
        const float* __restrict__ b_ih, float* __restrict__ hout, int N) {
    __shared__ __align__(16) u16 wb[16 * 512];
    __shared__ float mld[4][16][68];   // padded: stride 68 -> <=2-way bank conflicts
    int t = threadIdx.x, l = t & 63, w = t >> 6, g = l >> 4;
    int n0 = blockIdx.x * 64 + w * 16;
    int node = n0 + (l & 15);
    int nc = node < N ? node : N - 1;
    const float* xrow = x + (size_t)nc * 64 + g * 8;

    // x fragments (B operand), fp16
    h8v xh[2];
    #pragma unroll
    for (int kc = 0; kc < 2; kc++) {
        f32x4 a = *(const f32x4*)(xrow + kc * 32);
        f32x4 b = *(const f32x4*)(xrow + kc * 32 + 4);
        #pragma unroll
        for (int j = 0; j < 8; j++) xh[kc][j] = (_Float16)(j < 4 ? a[j] : b[j - 4]);
    }

    f32x4 acc1[16];
    #pragma unroll
    for (int ct = 0; ct < 16; ct++) acc1[ct] = (f32x4)(0.f);

    for (int kc = 0; kc < 2; kc++) {
        if (kc) __syncthreads();
        const uint4* ghp = (const uint4*)(w1 + kc * 16 * 512);
        uint4* lh = (uint4*)wb;
        for (int i = t; i < 1024; i += 256) lh[i] = ghp[i];
        __syncthreads();
        #pragma unroll
        for (int ct = 0; ct < 16; ct++) {
            h8v wh = *(const h8v*)(wb + ct * 512 + l * 8);
            acc1[ct] = __builtin_amdgcn_mfma_f32_16x16x32_f16(wh, xh[kc], acc1[ct], 0, 0, 0);
        }
    }

    // epilogue 1: m -> LDS ; gh = acc1[4..15] + b_hh (in place)
    #pragma unroll
    for (int ct = 0; ct < 4; ct++) {
        int c = ct * 16 + g * 4;
        f32x4 av = (f32x4)(0.f);
        if (node < N) av = *(const f32x4*)(agg + (size_t)node * 64 + c);
        f32x4 cb = *(const f32x4*)(conv_b + c);
        f32x4 mv;
        #pragma unroll
        for (int r = 0; r < 4; r++) mv[r] = fmaxf(acc1[ct][r] + av[r] + cb[r], 0.f);
        *(f32x4*)(&mld[w][l & 15][c]) = mv;
    }
    #pragma unroll
    for (int ct = 4; ct < 16; ct++) {
        int c = (ct - 4) * 16 + g * 4;
        f32x4 bh = *(const f32x4*)(b_hh + c);
        #pragma unroll
        for (int r = 0; r < 4; r++) acc1[ct][r] += bh[r];
    }
    __syncthreads();

    // m fragments from LDS, fp16
    h8v mh[2];
    #pragma unroll
    for (int kc = 0; kc < 2; kc++) {
        const float* mr = &mld[w][l & 15][kc * 32 + g * 8];
        f32x4 a = *(const f32x4*)(mr);
        f32x4 b = *(const f32x4*)(mr + 4);
        #pragma unroll
        for (int j = 0; j < 8; j++) mh[kc][j] = (_Float16)(j < 4 ? a[j] : b[j - 4]);
    }

    f32x4 acc2[12];
    #pragma unroll
    for (int ct = 0; ct < 12; ct++) acc2[ct] = (f32x4)(0.f);

    for (int kc = 0; kc < 2; kc++) {
        __syncthreads();   // protect wb reuse
        const uint4* ghp = (const uint4*)(w2 + kc * 12 * 512);
        uint4* lh = (uint4*)wb;
        for (int i = t; i < 768; i += 256) lh[i] = ghp[i];
        __syncthreads();
        #pragma unroll
        for (int ct = 0; ct < 12; ct++) {
            h8v wh = *(const h8v*)(wb + ct * 512 + l * 8);
            acc2[ct] = __builtin_amdgcn_mfma_f32_16x16x32_f16(wh, mh[kc], acc2[ct], 0, 0, 0);
        }
    }

    // epilogue 2: gates. gi col c=q*16+g*4+r: r acc2[q], z acc2[4+q], n acc2[8+q];
    // gh: r acc1[4+q], z acc1[8+q], n acc1[12+q]. All lane-local.
    #pragma unroll
    for (int q = 0; q < 4; q++) {
        int c = q * 16 + g * 4;
        f32x4 bir = *(const f32x4*)(b_ih + c);
        f32x4 biz = *(const f32x4*)(b_ih + 64 + c);
        f32x4 bin = *(const f32x4*)(b_ih + 128 + c);
        f32x4 hv = (f32x4)(0.f);
        if (node < N) hv = *(const f32x4*)(x + (size_t)node * 64 + c);
        f32x4 outv;
        #pragma unroll
        for (int r = 0; r < 4; r++) {
            float rr = sigm(acc2[q][r] + bir[r] + acc1[4 + q][r]);
            float zz = sigm(acc2[4 + q][r] + biz[r] + acc1[8 + q][r]);
            float nt = tanh_f(acc2[8 + q][r] + bin[r] + rr * acc1[12 + q][r]);
            outv[r] = (1.f - zz) * nt + zz * hv[r];
        }
        if (node < N) *(f32x4*)(hout + (size_t)node * 64 + c) = outv;
    }
}

extern "C" void kernel_launch(void* const* d_in, const int* in_sizes, int n_in,
                              void* d_out, int out_size, void* d_ws, size_t ws_size,
                              hipStream_t stream) {
    const float* x_in   = (const float*)d_in[0];
    const int*   ei     = (const int*)d_in[1];
    const float* ea     = (const float*)d_in[2];
    const float* lin0_w = (const float*)d_in[3];
    const float* lin0_b = (const float*)d_in[4];
    const float* nn_w   = (const float*)d_in[5];
    const float* nn_b   = (const float*)d_in[6];
    const float* root   = (const float*)d_in[7];
    const float* conv_b = (const float*)d_in[8];
    const float* w_ih   = (const float*)d_in[9];
    const float* w_hh   = (const float*)d_in[10];
    const float* b_ih   = (const float*)d_in[11];
    const float* b_hh   = (const float*)d_in[12];

    int N = in_sizes[0] / 32;
    int E = in_sizes[1] / 2;

    char* ws = (char*)d_ws;
    size_t off = 0;
    auto alloc = [&](size_t bytes) { char* p = ws + off; off += (bytes + 255) & ~(size_t)255; return p; };
    float* xbuf = (float*)alloc((size_t)N * 64 * 4);
    float* agg  = (float*)alloc((size_t)N * 64 * 4);
    u16*   Tbuf = (u16*)alloc((size_t)N * TW * 2);
    u16*   wf   = (u16*)alloc((size_t)2 * 68 * 64 * 8 * 2);
    u16*   w1   = (u16*)alloc(16384 * 2);
    u16*   w2   = (u16*)alloc(12288 * 2);
    u16*   w0   = (u16*)alloc(2048 * 2);
    (void)ws_size;

    hipLaunchKernelGGL(k_prepW, dim3(272), dim3(256), 0, stream, nn_w, nn_b, wf);
    hipLaunchKernelGGL(k_prepW12, dim3(120), dim3(256), 0, stream, root, w_hh, w_ih, lin0_w, w1, w2, w0);
    hipLaunchKernelGGL(k_lin0, dim3((N + 63) / 64), dim3(256), 0, stream, x_in, w0, lin0_b, xbuf, N);

    for (int it = 0; it < 3; it++) {
        hipLaunchKernelGGL(k_A_mfma, dim3((N + 63) / 64, 4), dim3(256), 0, stream, xbuf, wf, Tbuf, N);
        hipMemsetAsync(agg, 0, (size_t)N * 64 * 4, stream);
        hipLaunchKernelGGL(k_B, dim3((E * 64 + 255) / 256), dim3(256), 0, stream, Tbuf, ei, ea, agg, E);
        float* hout = (it == 2) ? (float*)d_out : xbuf;
        hipLaunchKernelGGL(k_C, dim3((N + 63) / 64), dim3(256), 0, stream, xbuf, agg,
                           w1, w2, conv_b, b_hh, b_ih, hout, N);
    }
}